// Round 7
// baseline (170.609 us; speedup 1.0000x reference)
//
#include <hip/hip_runtime.h>
#include <hip/hip_bf16.h>
#include <stdint.h>

// Problem geometry
#define B_   64
#define C_   512
#define L_   784      // 28*28
#define LP   800      // padded row length (25 * 32), pad is zero-filled
#define TILE 128
#define KSTEPS 25
#define NPAIR 10      // unordered tile pairs (i<=j) of 4 row-tiles

#define AS1 __attribute__((address_space(1)))
#define AS3 __attribute__((address_space(3)))

typedef __attribute__((ext_vector_type(8))) __bf16 bf16x8;
typedef __attribute__((ext_vector_type(4))) float  f32x4;

#define WAITV6  asm volatile("s_waitcnt vmcnt(6)"  ::: "memory")
#define WAITV0  asm volatile("s_waitcnt vmcnt(0)"  ::: "memory")
#define SBAR    __builtin_amdgcn_s_barrier()
#define SCHED0  __builtin_amdgcn_sched_barrier(0)
#define GLD16(SRC, DST) __builtin_amdgcn_global_load_lds((AS1 const void*)(SRC), (AS3 void*)(DST), 16, 0, 0)
#define GLD4(SRC, DST)  __builtin_amdgcn_global_load_lds((AS1 const void*)(SRC), (AS3 void*)(DST), 4, 0, 0)

// LDS buffer layout (bytes): Ti@0 (8K), Si@8192 (8K), Tj@16384 (4K), Sj@20480 (4K)
#define BUF_SHORTS 12288   // 24KB per buffer

// ---------------------------------------------------------------------------
// round-to-nearest-even float -> bf16 bits (data has no NaN/Inf)
__device__ inline unsigned short f2bf(float x) {
    union { float f; uint32_t u; } a; a.f = x;
    uint32_t u = a.u;
    return (unsigned short)((u + 0x7fffu + ((u >> 16) & 1u)) >> 16);
}

// ---------------------------------------------------------------------------
__global__ void init_kernel(float* partials) {
    if (threadIdx.x < 16) partials[threadIdx.x] = 0.0f;
}

// ---------------------------------------------------------------------------
// Pass 1: L2-normalize each [784] row (fp32), write bf16 padded to LP=800.
// One wave per row; 4 waves (256 threads) per block.  Already ~HBM roofline.
__global__ __launch_bounds__(256) void normalize_kernel(
    const float* __restrict__ fs, const float* __restrict__ ft,
    unsigned short* __restrict__ outT, unsigned short* __restrict__ outS)
{
    int gwave = blockIdx.x * 4 + (threadIdx.x >> 6);
    int lane  = threadIdx.x & 63;
    int mat   = gwave >> 15;          // 0 -> t, 1 -> s  (32768 rows each)
    int row   = gwave & 32767;

    const float* src = (mat == 0 ? ft : fs) + (size_t)row * L_;
    unsigned short* dst = (mat == 0 ? outT : outS) + (size_t)row * LP;

    float4 v[4];
    float ss = 0.0f;
#pragma unroll
    for (int it = 0; it < 4; ++it) {
        int c = it * 64 + lane;       // float4 chunk index, 196 chunks/row
        if (c < 196) {
            v[it] = reinterpret_cast<const float4*>(src)[c];
            ss += v[it].x * v[it].x + v[it].y * v[it].y
                + v[it].z * v[it].z + v[it].w * v[it].w;
        }
    }
#pragma unroll
    for (int m = 32; m >= 1; m >>= 1) ss += __shfl_xor(ss, m, 64);
    float rn = 1.0f / fmaxf(sqrtf(ss), 1e-12f);

#pragma unroll
    for (int it = 0; it < 4; ++it) {
        int c = it * 64 + lane;
        if (c < 196) {
            ushort4 o;
            o.x = f2bf(v[it].x * rn);
            o.y = f2bf(v[it].y * rn);
            o.z = f2bf(v[it].z * rn);
            o.w = f2bf(v[it].w * rn);
            *reinterpret_cast<ushort4*>(dst + (size_t)c * 4) = o;
        } else if (c < 200) {         // zero the 16-element pad (784..799)
            *reinterpret_cast<ushort4*>(dst + (size_t)c * 4) = make_ushort4(0, 0, 0, 0);
        }
    }
}

// ---------------------------------------------------------------------------
// Stage one K-step: A-side panels Ti,Si (128 rows x 32k, 8KB each, one x16B
// chunk/thread) + B-side panels Tj,Sj (64 rows x 32k, 4KB each, two x4B
// dwords/thread). 6 GLD per thread -> vmcnt multiples of 6.
// LDS dest linear (wave-uniform + lane*size); T2 XOR-swizzle applied by
// PRE-SWIZZLING the global source slot (involution == read-side XOR).
__device__ __forceinline__ void stage_ab(
    const unsigned short* __restrict__ Ti, const unsigned short* __restrict__ Si,
    const unsigned short* __restrict__ Tj, const unsigned short* __restrict__ Sj,
    int k0, unsigned short* base, int tid, int wid)
{
    // A panels
    {
        int r  = tid >> 2;                    // panel row 0..127
        int sl = (tid & 3) ^ ((r >> 1) & 3);  // swizzled 16B slot in row
        size_t goff = (size_t)r * LP + k0 + sl * 8;
        unsigned short* d = base + wid * 512; // 1KB per wave
        GLD16(Ti + goff, d);
        GLD16(Si + goff, d + 4096);           // Si at +8KB
    }
    // B panels (size-4 loads, 2 rounds)
#pragma unroll
    for (int q = 0; q < 2; ++q) {
        int D   = q * 512 + tid;              // dword id 0..1023
        int r   = D >> 4;                     // panel row 0..63 (16 dw/row)
        int din = D & 15;
        int sl  = (din >> 2) ^ ((r >> 1) & 3);
        int w   = din & 3;
        size_t gdw = (size_t)r * (LP / 2) + (k0 / 2) + sl * 4 + w;
        unsigned int* dB = (unsigned int*)(base + 8192) + q * 512 + wid * 64;
        GLD4((const unsigned int*)Tj + gdw, dB);
        GLD4((const unsigned int*)Sj + gdw, dB + 1024);   // Sj at +4KB
    }
}

// ---------------------------------------------------------------------------
// Pass 2 (fused): one block per (batch, pair{i<=j}, col-half). Full K per
// block (sum-of-squares is NOT additive over K). Computes all four products
// tt,st,ts,ss over rows[i-tile,128] x cols[j-tile half,64].
// 8 waves in 4x2; each wave owns 32x32 of each product -> acc = 64 VGPR.
// __launch_bounds__(512,4) caps regs at 128 -> 2 blocks/CU resident.
// Triple-buffered 72KB LDS, depth-2 prefetch, counted vmcnt(6).
__global__ __launch_bounds__(512, 4) void gram_kernel(
    const unsigned short* __restrict__ Tn,
    const unsigned short* __restrict__ Sn,
    float* __restrict__ partials)
{
    int blk = blockIdx.x;
    int ch  = blk & 1;                 // column half of the j-tile
    int pb  = blk >> 1;
    int b   = pb / NPAIR;
    int t   = pb % NPAIR;

    int i, j;
    if      (t < 4) { i = 0; j = t;     }
    else if (t < 7) { i = 1; j = t - 3; }
    else if (t < 9) { i = 2; j = t - 5; }
    else            { i = 3; j = 3;     }

    // off-diag pair represents 2 symmetric tiles for tt/ss (w=2); st & ts are
    // distinct tiles (w=1). Diagonal: tt/ss w=1; st counted twice -> w=0.5.
    float wsym   = (i == j) ? 1.0f : 2.0f;
    float wcross = (i == j) ? 0.5f : 1.0f;

    const unsigned short* Ti = Tn + (size_t)b * C_ * LP + (size_t)i * TILE * LP;
    const unsigned short* Si = Sn + (size_t)b * C_ * LP + (size_t)i * TILE * LP;
    const unsigned short* Tj = Tn + (size_t)b * C_ * LP + ((size_t)j * TILE + ch * 64) * LP;
    const unsigned short* Sj = Sn + (size_t)b * C_ * LP + ((size_t)j * TILE + ch * 64) * LP;

    // 3 buffers x 24KB = 72KB
    __shared__ unsigned short lds[3 * BUF_SHORTS];
    __shared__ float red[8];

    int tid  = threadIdx.x;
    int wid  = tid >> 6;
    int lane = tid & 63;

    int rA = (wid >> 1) * 32 + (lane & 15);      // output row block (0..127)
    int rB = (wid & 1) * 32 + (lane & 15);       // output col block (0..63)
    int kb = (lane >> 4) * 16;                   // 16B k-slot (bytes)
    // swizzled byte offsets (row stride 64B); XOR key (row>>1)&3 is invariant
    // under row+=16, so the +1024B frag steps remain valid
    int aByte = rA * 64 + (kb ^ (((rA >> 1) & 3) << 4));
    int bByte = rB * 64 + (kb ^ (((rB >> 1) & 3) << 4));

    f32x4 att[2][2] = {}, ast[2][2] = {}, ats[2][2] = {}, ass[2][2] = {};

    unsigned short* c0 = lds;
    unsigned short* c1 = lds + BUF_SHORTS;
    unsigned short* c2 = lds + 2 * BUF_SHORTS;

    // prologue: prefetch tiles 0,1 (12 loads/thread outstanding)
    stage_ab(Ti, Si, Tj, Sj, 0,  c0, tid, wid);
    stage_ab(Ti, Si, Tj, Sj, 32, c1, tid, wid);
    WAITV6;                 // tile 0 landed; tile 1's 6 loads in flight
    SBAR; SCHED0;

#define COMPUTE_STEP(BUF)                                                              \
    {                                                                                  \
        const char* bufc = (const char*)(BUF);                                         \
        bf16x8 fTi[2], fSi[2], fTj[2], fSj[2];                                         \
        _Pragma("unroll")                                                              \
        for (int m = 0; m < 2; ++m) {                                                  \
            fTi[m] = *reinterpret_cast<const bf16x8*>(bufc +         aByte + m * 1024);\
            fSi[m] = *reinterpret_cast<const bf16x8*>(bufc +  8192 + aByte + m * 1024);\
        }                                                                              \
        _Pragma("unroll")                                                              \
        for (int n = 0; n < 2; ++n) {                                                  \
            fTj[n] = *reinterpret_cast<const bf16x8*>(bufc + 16384 + bByte + n * 1024);\
            fSj[n] = *reinterpret_cast<const bf16x8*>(bufc + 20480 + bByte + n * 1024);\
        }                                                                              \
        __builtin_amdgcn_s_setprio(1);                                                 \
        _Pragma("unroll")                                                              \
        for (int m = 0; m < 2; ++m)                                                    \
            _Pragma("unroll")                                                          \
            for (int n = 0; n < 2; ++n) {                                              \
                att[m][n] = __builtin_amdgcn_mfma_f32_16x16x32_bf16(fTi[m], fTj[n], att[m][n], 0, 0, 0); \
                ast[m][n] = __builtin_amdgcn_mfma_f32_16x16x32_bf16(fTi[m], fSj[n], ast[m][n], 0, 0, 0); \
                ats[m][n] = __builtin_amdgcn_mfma_f32_16x16x32_bf16(fSi[m], fTj[n], ats[m][n], 0, 0, 0); \
                ass[m][n] = __builtin_amdgcn_mfma_f32_16x16x32_bf16(fSi[m], fSj[n], ass[m][n], 0, 0, 0); \
            }                                                                          \
        __builtin_amdgcn_s_setprio(0);                                                 \
    }

    // main loop: s = 0..KSTEPS-3; stage tile s+2, compute s, wait tile s+1
    for (int s = 0; s < KSTEPS - 2; ++s) {
        stage_ab(Ti, Si, Tj, Sj, (s + 2) * 32, c2, tid, wid);
        COMPUTE_STEP(c0);
        WAITV6;             // tile s+1 landed; tile s+2's 6 loads in flight
        SBAR; SCHED0;
        unsigned short* tmp = c0; c0 = c1; c1 = c2; c2 = tmp;
    }
    // s = KSTEPS-2: compute, wait last tile fully
    COMPUTE_STEP(c0);
    WAITV0;
    SBAR; SCHED0;
    { unsigned short* tmp = c0; c0 = c1; c1 = tmp; }
    // s = KSTEPS-1: final compute
    COMPUTE_STEP(c0);

    // ---- epilogue: weighted sum of squares (layout-free) ----
    float stt = 0.0f, sss = 0.0f, sst = 0.0f, sts = 0.0f;
#pragma unroll
    for (int m = 0; m < 2; ++m)
#pragma unroll
        for (int n = 0; n < 2; ++n)
#pragma unroll
            for (int q = 0; q < 4; ++q) {
                float x0 = att[m][n][q]; stt += x0 * x0;
                float x1 = ass[m][n][q]; sss += x1 * x1;
                float x2 = ast[m][n][q]; sst += x2 * x2;
                float x3 = ats[m][n][q]; sts += x3 * x3;
            }
    float v = wsym * (stt + sss) - 2.0f * wcross * (sst + sts);
#pragma unroll
    for (int m = 32; m >= 1; m >>= 1) v += __shfl_xor(v, m, 64);
    if (lane == 0) red[wid] = v;
    __syncthreads();
    if (tid == 0) {
        float tot = 0.0f;
#pragma unroll
        for (int q = 0; q < 8; ++q) tot += red[q];
        atomicAdd(&partials[0], tot);
    }
}

// ---------------------------------------------------------------------------
__global__ void finalize_kernel(const float* __restrict__ partials, float* __restrict__ out) {
    // mean over B*C*C = 64*512*512 = 16777216
    out[0] = partials[0] * (1.0f / 16777216.0f);
}

// ---------------------------------------------------------------------------
extern "C" void kernel_launch(void* const* d_in, const int* in_sizes, int n_in,
                              void* d_out, int out_size, void* d_ws, size_t ws_size,
                              hipStream_t stream) {
    const float* fs = (const float*)d_in[0];   // fm_s
    const float* ft = (const float*)d_in[1];   // fm_t
    float* out = (float*)d_out;

    char* ws = (char*)d_ws;
    float* partials = (float*)ws;                                  // 64 B
    unsigned short* Tn = (unsigned short*)(ws + 256);
    unsigned short* Sn = (unsigned short*)(ws + 256 + (size_t)B_ * C_ * LP * 2);
    // total ws use: 256 + 2*64*512*800*2 = ~104.9 MB

    hipLaunchKernelGGL(init_kernel, dim3(1), dim3(64), 0, stream, partials);
    hipLaunchKernelGGL(normalize_kernel, dim3((2 * B_ * C_) / 4), dim3(256), 0, stream,
                       fs, ft, Tn, Sn);
    hipLaunchKernelGGL(gram_kernel, dim3(B_ * NPAIR * 2), dim3(512), 0, stream,
                       Tn, Sn, partials);
    hipLaunchKernelGGL(finalize_kernel, dim3(1), dim3(1), 0, stream, partials, out);
}

// Round 8
// 126.206 us; speedup vs baseline: 1.3518x; 1.3518x over previous
//
#include <hip/hip_runtime.h>
#include <hip/hip_bf16.h>
#include <stdint.h>

// Problem geometry
#define B_   64
#define C_   512
#define L_   784      // 28*28
#define LP   800      // padded row length (25 * 32), pad is zero-filled
#define TILE 128
#define KSTEPS 25
#define NPAIR 10      // unordered tile pairs (i<=j) of 4 row-tiles
#define NXCD 8

#define AS1 __attribute__((address_space(1)))
#define AS3 __attribute__((address_space(3)))

typedef __attribute__((ext_vector_type(8))) __bf16 bf16x8;
typedef __attribute__((ext_vector_type(4))) float  f32x4;

#define WAITV4  asm volatile("s_waitcnt vmcnt(4)"  ::: "memory")
#define WAITV0  asm volatile("s_waitcnt vmcnt(0)"  ::: "memory")
#define LGKM0   asm volatile("s_waitcnt lgkmcnt(0)" ::: "memory")
#define SBAR    __builtin_amdgcn_s_barrier()
#define SCHED0  __builtin_amdgcn_sched_barrier(0)
#define GLD16(SRC, DST) __builtin_amdgcn_global_load_lds((AS1 const void*)(SRC), (AS3 void*)(DST), 16, 0, 0)

// ---------------------------------------------------------------------------
// round-to-nearest-even float -> bf16 bits (data has no NaN/Inf)
__device__ inline unsigned short f2bf(float x) {
    union { float f; uint32_t u; } a; a.f = x;
    uint32_t u = a.u;
    return (unsigned short)((u + 0x7fffu + ((u >> 16) & 1u)) >> 16);
}

// ---------------------------------------------------------------------------
__global__ void init_kernel(float* partials) {
    if (threadIdx.x < 16) partials[threadIdx.x] = 0.0f;
}

// ---------------------------------------------------------------------------
// Pass 1: L2-normalize each [784] row (fp32), write bf16 padded to LP=800.
// One wave per row; 4 waves (256 threads) per block.  Already ~HBM roofline.
__global__ __launch_bounds__(256) void normalize_kernel(
    const float* __restrict__ fs, const float* __restrict__ ft,
    unsigned short* __restrict__ outT, unsigned short* __restrict__ outS)
{
    int gwave = blockIdx.x * 4 + (threadIdx.x >> 6);
    int lane  = threadIdx.x & 63;
    int mat   = gwave >> 15;          // 0 -> t, 1 -> s  (32768 rows each)
    int row   = gwave & 32767;

    const float* src = (mat == 0 ? ft : fs) + (size_t)row * L_;
    unsigned short* dst = (mat == 0 ? outT : outS) + (size_t)row * LP;

    float4 v[4];
    float ss = 0.0f;
#pragma unroll
    for (int it = 0; it < 4; ++it) {
        int c = it * 64 + lane;       // float4 chunk index, 196 chunks/row
        if (c < 196) {
            v[it] = reinterpret_cast<const float4*>(src)[c];
            ss += v[it].x * v[it].x + v[it].y * v[it].y
                + v[it].z * v[it].z + v[it].w * v[it].w;
        }
    }
#pragma unroll
    for (int m = 32; m >= 1; m >>= 1) ss += __shfl_xor(ss, m, 64);
    float rn = 1.0f / fmaxf(sqrtf(ss), 1e-12f);

#pragma unroll
    for (int it = 0; it < 4; ++it) {
        int c = it * 64 + lane;
        if (c < 196) {
            ushort4 o;
            o.x = f2bf(v[it].x * rn);
            o.y = f2bf(v[it].y * rn);
            o.z = f2bf(v[it].z * rn);
            o.w = f2bf(v[it].w * rn);
            *reinterpret_cast<ushort4*>(dst + (size_t)c * 4) = o;
        } else if (c < 200) {         // zero the 16-element pad (784..799)
            *reinterpret_cast<ushort4*>(dst + (size_t)c * 4) = make_ushort4(0, 0, 0, 0);
        }
    }
}

// ---------------------------------------------------------------------------
// Pass 2 (fused, 4-phase schedule): one block per (batch, pair{i<=j}), full K.
// Stages panels T_i,T_j,S_i,S_j (8KB each) once per K-step; computes all four
// 128x128 products tt,st,ts,ss (sum-of-squares is transpose-invariant so the
// bipartite operand choice is valid). 8 waves; wave w owns rows (w>>2)*64,
// cols (w&3)*32 of every product: 12 LDS frags -> 32 MFMA per step, split
// into 4 phases of {ds_read || 1 stage-GLD -> bar -> lgkm0 -> 8 MFMA -> bar}.
// Counted vmcnt(4) once per K-step (T4); setprio around MFMA (T5);
// both-sides XOR swizzle (T2, measured 0 conflicts); XCD block swizzle (T1).
__global__ __launch_bounds__(512, 1) void gram_kernel(
    const unsigned short* __restrict__ Tn,
    const unsigned short* __restrict__ Sn,
    float* __restrict__ partials)
{
    // T1: bijective XCD chunk swizzle (640 = 8 XCDs x 80; 8 batches/XCD)
    int blk = (blockIdx.x % NXCD) * (B_ * NPAIR / NXCD) + blockIdx.x / NXCD;
    int b   = blk / NPAIR;
    int t   = blk % NPAIR;

    int i, j;
    if      (t < 4) { i = 0; j = t;     }
    else if (t < 7) { i = 1; j = t - 3; }
    else if (t < 9) { i = 2; j = t - 5; }
    else            { i = 3; j = 3;     }

    // off-diag pair represents 2 symmetric tiles for tt/ss (w=2); st & ts are
    // distinct tiles (w=1). Diagonal: tt/ss w=1; st counted twice -> w=0.5.
    float wsym   = (i == j) ? 1.0f : 2.0f;
    float wcross = (i == j) ? 0.5f : 1.0f;

    const unsigned short* Ti = Tn + (size_t)b * C_ * LP + (size_t)i * TILE * LP;
    const unsigned short* Tj = Tn + (size_t)b * C_ * LP + (size_t)j * TILE * LP;
    const unsigned short* Si = Sn + (size_t)b * C_ * LP + (size_t)i * TILE * LP;
    const unsigned short* Sj = Sn + (size_t)b * C_ * LP + (size_t)j * TILE * LP;

    // 3 buffers x 32KB = 96KB; panel layout per buffer (shorts):
    // Ti@0, Tj@4096, Si@8192, Sj@12288
    __shared__ unsigned short lds[3 * 16384];
    __shared__ float red[8];

    int tid  = threadIdx.x;
    int wid  = tid >> 6;
    int lane = tid & 63;

    // staging addresses (T2 swizzle by pre-swizzled global source slot)
    int sr  = tid >> 2;                      // panel row 0..127
    int ssl = (tid & 3) ^ ((sr >> 1) & 3);   // swizzled 16B slot in row
    const size_t gOff = (size_t)sr * LP + ssl * 8;   // + k0 per step
    const int dOff = wid * 512;              // shorts; lane*16B implicit

    // fragment read addresses (swizzled read side, involution matches source)
    int rA = (wid >> 2) * 64 + (lane & 15);  // A-side panel row
    int rB = (wid & 3) * 32 + (lane & 15);   // B-side panel row
    int kb = (lane >> 4) * 16;               // 16B k-slot (bytes)
    int aByte = rA * 64 + (kb ^ (((rA >> 1) & 3) << 4));
    int bByte = rB * 64 + (kb ^ (((rB >> 1) & 3) << 4));

    f32x4 att[4][2] = {}, ast[4][2] = {}, ats[4][2] = {}, ass[4][2] = {};

    unsigned short* c0 = lds;
    unsigned short* c1 = lds + 16384;
    unsigned short* c2 = lds + 32768;

    // prologue: stage tiles 0,1 (8 GLD/thread outstanding)
    {
        GLD16(Ti + gOff, c0 + dOff);  GLD16(Tj + gOff, c0 + 4096 + dOff);
        GLD16(Si + gOff, c0 + 8192 + dOff);  GLD16(Sj + gOff, c0 + 12288 + dOff);
        GLD16(Ti + gOff + 32, c1 + dOff);  GLD16(Tj + gOff + 32, c1 + 4096 + dOff);
        GLD16(Si + gOff + 32, c1 + 8192 + dOff);  GLD16(Sj + gOff + 32, c1 + 12288 + dOff);
    }
    WAITV4;                 // tile 0 landed; tile 1's 4 loads in flight
    SBAR; SCHED0;

#define MFMA8(ACC, FA, FB)                                                             \
    _Pragma("unroll")                                                                  \
    for (int m = 0; m < 4; ++m)                                                        \
        _Pragma("unroll")                                                              \
        for (int n = 0; n < 2; ++n)                                                    \
            ACC[m][n] = __builtin_amdgcn_mfma_f32_16x16x32_bf16(FA[m], FB[n], ACC[m][n], 0, 0, 0);

// One K-step, 4 phases. DOSTAGE is a literal 0/1; K2 = k-offset (shorts) of
// tile t+2; NBUF = its destination buffer; ENDW = end-of-step vmcnt wait.
#define KSTEP(BUF, NBUF, K2, DOSTAGE, ENDW)                                            \
    {                                                                                  \
        const char* bufc = (const char*)(BUF);                                         \
        bf16x8 fTi[4], fSi[4], fTj[2], fSj[2];                                         \
        /* ---- phase 0: read fTi,fTj | stage Ti(t+2) | mfma tt ---- */                \
        _Pragma("unroll")                                                              \
        for (int m = 0; m < 4; ++m)                                                    \
            fTi[m] = *reinterpret_cast<const bf16x8*>(bufc + aByte + m * 1024);        \
        _Pragma("unroll")                                                              \
        for (int n = 0; n < 2; ++n)                                                    \
            fTj[n] = *reinterpret_cast<const bf16x8*>(bufc + 8192 + bByte + n * 1024); \
        if (DOSTAGE) GLD16(Ti + gOff + (K2), (NBUF) + dOff);                           \
        SBAR; LGKM0; SCHED0;                                                           \
        __builtin_amdgcn_s_setprio(1);                                                 \
        MFMA8(att, fTi, fTj);                                                          \
        __builtin_amdgcn_s_setprio(0);                                                 \
        SBAR;                                                                          \
        /* ---- phase 1: read fSj | stage Tj(t+2) | mfma st ---- */                    \
        _Pragma("unroll")                                                              \
        for (int n = 0; n < 2; ++n)                                                    \
            fSj[n] = *reinterpret_cast<const bf16x8*>(bufc + 24576 + bByte + n * 1024);\
        if (DOSTAGE) GLD16(Tj + gOff + (K2), (NBUF) + 4096 + dOff);                    \
        SBAR; LGKM0; SCHED0;                                                           \
        __builtin_amdgcn_s_setprio(1);                                                 \
        MFMA8(ast, fTi, fSj);                                                          \
        __builtin_amdgcn_s_setprio(0);                                                 \
        SBAR;                                                                          \
        /* ---- phase 2: read fSi | stage Si(t+2) | mfma ts ---- */                    \
        _Pragma("unroll")                                                              \
        for (int m = 0; m < 4; ++m)                                                    \
            fSi[m] = *reinterpret_cast<const bf16x8*>(bufc + 16384 + aByte + m * 1024);\
        if (DOSTAGE) GLD16(Si + gOff + (K2), (NBUF) + 8192 + dOff);                    \
        SBAR; LGKM0; SCHED0;                                                           \
        __builtin_amdgcn_s_setprio(1);                                                 \
        MFMA8(ats, fSi, fTj);                                                          \
        __builtin_amdgcn_s_setprio(0);                                                 \
        SBAR;                                                                          \
        /* ---- phase 3: stage Sj(t+2) | mfma ss | end-of-step wait ---- */            \
        if (DOSTAGE) GLD16(Sj + gOff + (K2), (NBUF) + 12288 + dOff);                   \
        __builtin_amdgcn_s_setprio(1);                                                 \
        MFMA8(ass, fSi, fSj);                                                          \
        __builtin_amdgcn_s_setprio(0);                                                 \
        ENDW;                                                                          \
        SBAR; SCHED0;                                                                  \
    }

    // main loop: s = 0..22; stage tile s+2 into c2, compute tile s from c0,
    // end-of-step vmcnt(4) completes tile s+1.
    for (int s = 0; s < KSTEPS - 2; ++s) {
        KSTEP(c0, c2, (s + 2) * 32, 1, WAITV4);
        unsigned short* tmp = c0; c0 = c1; c1 = c2; c2 = tmp;
    }
    // s = 23: no staging; complete last tile fully
    KSTEP(c0, c2, 0, 0, WAITV0);
    { unsigned short* tmp = c0; c0 = c1; c1 = tmp; }
    // s = 24: final compute, no waits needed
    KSTEP(c0, c2, 0, 0, (void)0);

    // ---- epilogue: weighted sum of squares (layout-free) ----
    float stt = 0.0f, sss = 0.0f, sst = 0.0f, sts = 0.0f;
#pragma unroll
    for (int m = 0; m < 4; ++m)
#pragma unroll
        for (int n = 0; n < 2; ++n)
#pragma unroll
            for (int q = 0; q < 4; ++q) {
                float x0 = att[m][n][q]; stt += x0 * x0;
                float x1 = ass[m][n][q]; sss += x1 * x1;
                float x2 = ast[m][n][q]; sst += x2 * x2;
                float x3 = ats[m][n][q]; sts += x3 * x3;
            }
    float v = wsym * (stt + sss) - 2.0f * wcross * (sst + sts);
#pragma unroll
    for (int m = 32; m >= 1; m >>= 1) v += __shfl_xor(v, m, 64);
    if (lane == 0) red[wid] = v;
    __syncthreads();
    if (tid == 0) {
        float tot = 0.0f;
#pragma unroll
        for (int q = 0; q < 8; ++q) tot += red[q];
        atomicAdd(&partials[0], tot);
    }
}

// ---------------------------------------------------------------------------
__global__ void finalize_kernel(const float* __restrict__ partials, float* __restrict__ out) {
    // mean over B*C*C = 64*512*512 = 16777216
    out[0] = partials[0] * (1.0f / 16777216.0f);
}

// ---------------------------------------------------------------------------
extern "C" void kernel_launch(void* const* d_in, const int* in_sizes, int n_in,
                              void* d_out, int out_size, void* d_ws, size_t ws_size,
                              hipStream_t stream) {
    const float* fs = (const float*)d_in[0];   // fm_s
    const float* ft = (const float*)d_in[1];   // fm_t
    float* out = (float*)d_out;

    char* ws = (char*)d_ws;
    float* partials = (float*)ws;                                  // 64 B
    unsigned short* Tn = (unsigned short*)(ws + 256);
    unsigned short* Sn = (unsigned short*)(ws + 256 + (size_t)B_ * C_ * LP * 2);
    // total ws use: 256 + 2*64*512*800*2 = ~104.9 MB

    hipLaunchKernelGGL(init_kernel, dim3(1), dim3(64), 0, stream, partials);
    hipLaunchKernelGGL(normalize_kernel, dim3((2 * B_ * C_) / 4), dim3(256), 0, stream,
                       fs, ft, Tn, Sn);
    hipLaunchKernelGGL(gram_kernel, dim3(B_ * NPAIR), dim3(512), 0, stream,
                       Tn, Sn, partials);
    hipLaunchKernelGGL(finalize_kernel, dim3(1), dim3(1), 0, stream, partials, out);
}